// Round 12
// baseline (39.156 us; speedup 1.0000x reference)
//
#include <hip/hip_runtime.h>
#include <cstdint>

#define DEVFN __device__ __forceinline__

struct U128 { unsigned long long lo, hi; };

// rotate right by s (1..127): bit q of result = bit (q+s)%128 of w
DEVFN U128 rotr128(U128 w, int s) {
    U128 r;
    if (s == 64) { r.lo = w.hi; r.hi = w.lo; return r; }
    if (s < 64) {
        r.lo = (w.lo >> s) | (w.hi << (64 - s));
        r.hi = (w.hi >> s) | (w.lo << (64 - s));
    } else {
        int t = s - 64;
        unsigned long long lo = w.hi, hi = w.lo;
        r.lo = (lo >> t) | (hi << (64 - t));
        r.hi = (hi >> t) | (lo << (64 - t));
    }
    return r;
}

// logical shift right by s (1..127)
DEVFN U128 shr128(U128 w, int s) {
    U128 r;
    if (s == 64) { r.lo = w.hi; r.hi = 0ull; return r; }
    if (s < 64) {
        r.lo = (w.lo >> s) | (w.hi << (64 - s));
        r.hi = w.hi >> s;
    } else {
        r.lo = w.hi >> (s - 64); r.hi = 0ull;
    }
    return r;
}

// KB: W0 -> G2 reduction (768 blocks, R10-identical) + Sm + counter zeroing.
__global__ __launch_bounds__(256) void kB(const int* __restrict__ x,
                                          const int* __restrict__ masks,
                                          const float* __restrict__ W0,
                                          float* __restrict__ Sm,
                                          float* __restrict__ G2,
                                          int* __restrict__ cnt) {
    int bid = blockIdx.x;
    int tid = threadIdx.x;

    if (bid == 768) {
        if (tid < 36)
            __hip_atomic_store(&cnt[tid], 0, __ATOMIC_RELAXED, __HIP_MEMORY_SCOPE_AGENT);
        int b = tid >> 2;        // 64 rows of x
        int rc = tid & 3;        // 4 chunks of 32 r's
        const int* xb = x + b * 128;
        U128 w; w.lo = 0ull; w.hi = 0ull;
        #pragma unroll
        for (int p = 0; p < 64; ++p) w.lo |= (unsigned long long)(xb[p] & 1) << p;
        #pragma unroll
        for (int p = 0; p < 64; ++p) w.hi |= (unsigned long long)(xb[64 + p] & 1) << p;
        int r0 = rc * 32;
        if (r0 & 32) { U128 t = rotr128(w, 32); w.lo ^= t.lo; w.hi ^= t.hi; }
        if (r0 & 64) { U128 t = rotr128(w, 64); w.lo ^= t.lo; w.hi ^= t.hi; }
        for (int rr = 0; rr < 32; ++rr) {
            int r = r0 + rr;
            int pc = __popcll(w.lo) + __popcll(w.hi);
            int sv = (r == 0) ? pc : (128 - pc);
            Sm[b * 128 + r] = (float)(2 * sv - 128);
            U128 t = rotr128(w, 1);
            w.lo ^= t.lo; w.hi ^= t.hi;
        }
        return;
    }

    int hc = bid & 3;            // 4 quarters of 256 h
    int y  = bid >> 2;           // 0..191 (r, segment) task
    int r, jstart, jend, slice;
    if (y < 128) { r = y >> 1; slice = y & 1; jstart = slice * 64; jend = (slice == 0) ? 64 : (128 - r); }
    else         { r = y - 64;  slice = 0;    jstart = 0;          jend = 128 - r; }
    int L = jend - jstart;       // 1..64

    int lane = tid & 63;
    int g    = tid >> 6;         // row-group 0..3

    __shared__ unsigned long long mw[3][2];
    __shared__ float cG[64];
    __shared__ float4 partG[4][64];

    if (tid < 128) {
        int half = tid >> 6;
        int lane_ = tid & 63;
        #pragma unroll
        for (int k = 0; k < 3; ++k) {
            unsigned long long bal = __ballot(masks[k * 128 + half * 64 + lane_] & 1);
            if (lane_ == 0) mw[k][half] = bal;
        }
    }
    __syncthreads();
    if (tid < 64) {
        int j = jstart + tid;
        int c = 0;
        #pragma unroll
        for (int k = 0; k < 3; ++k) {
            U128 m; m.lo = mw[k][0]; m.hi = mw[k][1];
            #pragma unroll
            for (int s = 1; s <= 64; s <<= 1) {
                if (r & s) { U128 t = shr128(m, s); m.lo ^= t.lo; m.hi ^= t.hi; }
            }
            int bit = (j < 64) ? (int)((m.lo >> j) & 1) : (int)((m.hi >> (j - 64)) & 1);
            c += bit;
        }
        cG[tid] = (float)(2 - c) * (1.0f / 256.0f);
    }
    __syncthreads();

    int off = r * 128 - (r * (r - 1)) / 2;
    const float* base = W0 + (size_t)(off + jstart) * 1024 + hc * 256 + lane * 4;
    float4 aG = {0.f, 0.f, 0.f, 0.f};
    #pragma unroll 4
    for (int jj = g; jj < L; jj += 4) {
        float4 v = *(const float4*)(base + (size_t)jj * 1024);
        float cg = cG[jj];
        aG.x += cg * v.x; aG.y += cg * v.y; aG.z += cg * v.z; aG.w += cg * v.w;
    }
    partG[g][lane] = aG;
    __syncthreads();

    if (tid < 64) {
        float4 sG = partG[0][tid];
        #pragma unroll
        for (int gg = 1; gg < 4; ++gg) {
            float4 pG = partG[gg][tid];
            sG.x += pG.x; sG.y += pG.y; sG.z += pG.z; sG.w += pG.w;
        }
        int row = slice * 128 + r;
        *(float4*)(G2 + (size_t)row * 1024 + hc * 256 + tid * 4) = sG;
    }
}

// kFE: fused layer-1 + layer-2 split-K + XCD-local last-arriver output stage.
// bid = G + 32*kc, G = hc*4+bs (0..31) -> all 16 kc-blocks of a group share
// XCD (bid%8 = G%8); z1part stays in that XCD's L2 (plain stores/loads).
// Cross-XCD data: outpart (2 KB) + cnt via agent-scope (LLC) ops only.
__global__ __launch_bounds__(256) void kFE(const float* __restrict__ G2,
                                           const float* __restrict__ Sm,
                                           const float* __restrict__ b0,
                                           const float* __restrict__ W1,
                                           const float* __restrict__ b1,
                                           const float* __restrict__ Wo,
                                           const float* __restrict__ bo,
                                           float* __restrict__ z1part,
                                           float* __restrict__ outpart,
                                           int* __restrict__ cnt,
                                           float* __restrict__ out) {
    int bid = blockIdx.x;
    int G  = bid & 31;            // group id; XCD = G%8
    int kc = bid >> 5;            // 0..15 (64 k each)
    int hc = G >> 2;              // 0..7  (128 h-cols each)
    int bs = G & 3;               // 0..3  (16 b each)
    int tid = threadIdx.x;

    __shared__ float W1sh[64][128];   // 32 KB
    __shared__ float Ssh[16][128];    // 8 KB (pre-shifted S - 128)
    __shared__ float h0sh[16][64];    // 4 KB
    __shared__ float wredLDS[4][4];
    __shared__ int lastFlag;

    #pragma unroll
    for (int t = 0; t < 32; ++t) {
        int idx = tid + t * 256;      // 0..8191
        int kk = idx >> 7, hcl = idx & 127;
        W1sh[kk][hcl] = W1[(kc * 64 + kk) * 1024 + hc * 128 + hcl];
    }
    #pragma unroll
    for (int t = 0; t < 8; ++t) {
        int idx = tid + t * 256;      // 0..2047
        int bl = idx >> 7, r = idx & 127;
        Ssh[bl][r] = Sm[(bs * 16 + bl) * 128 + r];
    }
    __syncthreads();

    // ---- Phase A: h0 sub-tile ----
    {
        int k = tid & 63;
        int bg = tid >> 6;
        const float* g2p = G2 + kc * 64 + k;
        float acc[4] = {0.f, 0.f, 0.f, 0.f};
        #pragma unroll 8
        for (int row = 0; row < 192; ++row) {
            float gv = g2p[row * 1024];
            int r = row & 127;
            #pragma unroll
            for (int bb = 0; bb < 4; ++bb)
                acc[bb] += Ssh[bg * 4 + bb][r] * gv;
        }
        float base = b0[kc * 64 + k];
        #pragma unroll
        for (int bb = 0; bb < 4; ++bb)
            h0sh[bg * 4 + bb][k] = fmaxf(base + acc[bb], 0.f);
    }
    __syncthreads();

    // ---- Phase B: z1part tile = h0sh (16x64) . W1sh (64x128) ----
    {
        int hcol = tid & 127;
        int bg2 = tid >> 7;
        float acc2[8];
        #pragma unroll
        for (int i = 0; i < 8; ++i) acc2[i] = 0.f;
        #pragma unroll 4
        for (int kk = 0; kk < 64; ++kk) {
            float w = W1sh[kk][hcol];
            #pragma unroll
            for (int bb = 0; bb < 8; ++bb)
                acc2[bb] += h0sh[bg2 * 8 + bb][kk] * w;
        }
        #pragma unroll
        for (int bb = 0; bb < 8; ++bb) {
            int bl = bg2 * 8 + bb;
            z1part[((size_t)(G * 16 + kc) * 16 + bl) * 128 + hcol] = acc2[bb];
        }
    }

    // ---- last-arriver stage 1 (XCD-local: all 16 producers share this L2) ----
    asm volatile("s_waitcnt vmcnt(0)" ::: "memory");
    __syncthreads();
    if (tid == 0) {
        int old = atomicAdd(&cnt[G], 1);
        lastFlag = (old == 15);
    }
    __syncthreads();
    if (!lastFlag) return;

    // cleanup: z1[b][h] over 16 kc, relu, dot with Wo slice (128 h)
    {
        int w = tid >> 6, l = tid & 63;
        float2 wo2 = *(const float2*)&Wo[hc * 128 + 2 * l];
        float2 b12 = *(const float2*)&b1[hc * 128 + 2 * l];
        const float* zb = z1part + (size_t)G * 16 * 2048;
        #pragma unroll
        for (int p = 0; p < 4; ++p) {
            int bl = p * 4 + w;
            float zx = b12.x, zy = b12.y;
            #pragma unroll
            for (int kc2 = 0; kc2 < 16; ++kc2) {
                float2 v = *(const float2*)&zb[(kc2 * 16 + bl) * 128 + 2 * l];
                zx += v.x; zy += v.y;
            }
            float val = fmaxf(zx, 0.f) * wo2.x + fmaxf(zy, 0.f) * wo2.y;
            #pragma unroll
            for (int off = 32; off >= 1; off >>= 1) val += __shfl_down(val, off);
            if (l == 0) wredLDS[p][w] = val;
        }
    }
    __syncthreads();
    if (tid < 16)
        __hip_atomic_store(&outpart[(bs * 8 + hc) * 16 + tid],
                           wredLDS[tid >> 2][tid & 3],
                           __ATOMIC_RELAXED, __HIP_MEMORY_SCOPE_AGENT);
    asm volatile("s_waitcnt vmcnt(0)" ::: "memory");
    __syncthreads();

    // ---- last-arriver stage 2 (cross-XCD via agent/LLC ops) ----
    if (tid == 0) {
        int old2 = atomicAdd(&cnt[32 + bs], 1);
        lastFlag = (old2 == 7);
    }
    __syncthreads();
    if (!lastFlag) return;

    if (tid < 16) {
        float s = bo[0];
        #pragma unroll
        for (int hc2 = 0; hc2 < 8; ++hc2)
            s += __hip_atomic_load(&outpart[(bs * 8 + hc2) * 16 + tid],
                                   __ATOMIC_RELAXED, __HIP_MEMORY_SCOPE_AGENT);
        out[bs * 16 + tid] = s;
    }
}

extern "C" void kernel_launch(void* const* d_in, const int* in_sizes, int n_in,
                              void* d_out, int out_size, void* d_ws, size_t ws_size,
                              hipStream_t stream) {
    const int*   x     = (const int*)d_in[0];    // (64,128) 0/1
    const int*   masks = (const int*)d_in[1];    // (3,128) 0/1
    const float* W0    = (const float*)d_in[2];  // (8256,1024)
    const float* b0    = (const float*)d_in[3];  // (1024)
    const float* W1    = (const float*)d_in[4];  // (1024,1024)
    const float* b1    = (const float*)d_in[5];  // (1024)
    const float* Wo    = (const float*)d_in[6];  // (1024,1)
    const float* bo    = (const float*)d_in[7];  // (1)
    float* out = (float*)d_out;                  // (64,1)

    char* ws = (char*)d_ws;
    float* Sm      = (float*)(ws);                     // 64*128*4      = 32 KB
    float* G2      = (float*)(ws + (32u   << 10));     // 192*1024*4    = 768 KB
    float* z1part  = (float*)(ws + (800u  << 10));     // 32*16*16*128*4= 4 MB
    float* outpart = (float*)(ws + (4896u << 10));     // 512*4         = 2 KB
    int*   cnt     = (int*)  (ws + (4898u << 10));     // 36 ints

    kB<<<769, 256, 0, stream>>>(x, masks, W0, Sm, G2, cnt);
    kFE<<<512, 256, 0, stream>>>(G2, Sm, b0, W1, b1, Wo, bo,
                                 z1part, outpart, cnt, out);
}

// Round 13
// 34.699 us; speedup vs baseline: 1.1285x; 1.1285x over previous
//
#include <hip/hip_runtime.h>
#include <cstdint>

#define DEVFN __device__ __forceinline__

struct U128 { unsigned long long lo, hi; };

// rotate right by s (1..127): bit q of result = bit (q+s)%128 of w
DEVFN U128 rotr128(U128 w, int s) {
    U128 r;
    if (s == 64) { r.lo = w.hi; r.hi = w.lo; return r; }
    if (s < 64) {
        r.lo = (w.lo >> s) | (w.hi << (64 - s));
        r.hi = (w.hi >> s) | (w.lo << (64 - s));
    } else {
        int t = s - 64;
        unsigned long long lo = w.hi, hi = w.lo;
        r.lo = (lo >> t) | (hi << (64 - t));
        r.hi = (hi >> t) | (lo << (64 - t));
    }
    return r;
}

// logical shift right by s (1..127)
DEVFN U128 shr128(U128 w, int s) {
    U128 r;
    if (s == 64) { r.lo = w.hi; r.hi = 0ull; return r; }
    if (s < 64) {
        r.lo = (w.lo >> s) | (w.hi << (64 - s));
        r.hi = w.hi >> s;
    } else {
        r.lo = w.hi >> (s - 64); r.hi = 0ull;
    }
    return r;
}

// KB: W0 -> G2 reduction (768 blocks) + Sm computation (block 768).
// Byte-identical to the R10 winner.
__global__ __launch_bounds__(256) void kB(const int* __restrict__ x,
                                          const int* __restrict__ masks,
                                          const float* __restrict__ W0,
                                          float* __restrict__ Sm,
                                          float* __restrict__ G2) {
    int bid = blockIdx.x;
    int tid = threadIdx.x;

    if (bid == 768) {
        int b = tid >> 2;        // 64 rows of x
        int rc = tid & 3;        // 4 chunks of 32 r's
        const int* xb = x + b * 128;
        U128 w; w.lo = 0ull; w.hi = 0ull;
        #pragma unroll
        for (int p = 0; p < 64; ++p) w.lo |= (unsigned long long)(xb[p] & 1) << p;
        #pragma unroll
        for (int p = 0; p < 64; ++p) w.hi |= (unsigned long long)(xb[64 + p] & 1) << p;
        int r0 = rc * 32;
        if (r0 & 32) { U128 t = rotr128(w, 32); w.lo ^= t.lo; w.hi ^= t.hi; }
        if (r0 & 64) { U128 t = rotr128(w, 64); w.lo ^= t.lo; w.hi ^= t.hi; }
        for (int rr = 0; rr < 32; ++rr) {
            int r = r0 + rr;
            int pc = __popcll(w.lo) + __popcll(w.hi);
            int sv = (r == 0) ? pc : (128 - pc);
            Sm[b * 128 + r] = (float)(2 * sv - 128);
            U128 t = rotr128(w, 1);
            w.lo ^= t.lo; w.hi ^= t.hi;
        }
        return;
    }

    int hc = bid & 3;            // 4 quarters of 256 h
    int y  = bid >> 2;           // 0..191 (r, segment) task
    int r, jstart, jend, slice;
    if (y < 128) { r = y >> 1; slice = y & 1; jstart = slice * 64; jend = (slice == 0) ? 64 : (128 - r); }
    else         { r = y - 64;  slice = 0;    jstart = 0;          jend = 128 - r; }
    int L = jend - jstart;       // 1..64

    int lane = tid & 63;
    int g    = tid >> 6;         // row-group 0..3

    __shared__ unsigned long long mw[3][2];
    __shared__ float cG[64];
    __shared__ float4 partG[4][64];

    if (tid < 128) {
        int half = tid >> 6;
        int lane_ = tid & 63;
        #pragma unroll
        for (int k = 0; k < 3; ++k) {
            unsigned long long bal = __ballot(masks[k * 128 + half * 64 + lane_] & 1);
            if (lane_ == 0) mw[k][half] = bal;
        }
    }
    __syncthreads();
    if (tid < 64) {
        int j = jstart + tid;
        int c = 0;
        #pragma unroll
        for (int k = 0; k < 3; ++k) {
            U128 m; m.lo = mw[k][0]; m.hi = mw[k][1];
            #pragma unroll
            for (int s = 1; s <= 64; s <<= 1) {
                if (r & s) { U128 t = shr128(m, s); m.lo ^= t.lo; m.hi ^= t.hi; }
            }
            int bit = (j < 64) ? (int)((m.lo >> j) & 1) : (int)((m.hi >> (j - 64)) & 1);
            c += bit;
        }
        cG[tid] = (float)(2 - c) * (1.0f / 256.0f);
    }
    __syncthreads();

    int off = r * 128 - (r * (r - 1)) / 2;
    const float* base = W0 + (size_t)(off + jstart) * 1024 + hc * 256 + lane * 4;
    float4 aG = {0.f, 0.f, 0.f, 0.f};
    #pragma unroll 4
    for (int jj = g; jj < L; jj += 4) {
        float4 v = *(const float4*)(base + (size_t)jj * 1024);
        float cg = cG[jj];
        aG.x += cg * v.x; aG.y += cg * v.y; aG.z += cg * v.z; aG.w += cg * v.w;
    }
    partG[g][lane] = aG;
    __syncthreads();

    if (tid < 64) {
        float4 sG = partG[0][tid];
        #pragma unroll
        for (int gg = 1; gg < 4; ++gg) {
            float4 pG = partG[gg][tid];
            sG.x += pG.x; sG.y += pG.y; sG.z += pG.z; sG.w += pG.w;
        }
        int row = slice * 128 + r;
        *(float4*)(G2 + (size_t)row * 1024 + hc * 256 + tid * 4) = sG;
    }
}

// kF: fused layer-1 + layer-2 split-K (R10 structure, LDS-vectorized).
// Phase A reads S via one ds_read_b128 broadcast per row (Ssh4[r][bg]);
// phase B reads h0 via two ds_read_b128 broadcasts per kk (h0t transposed).
__global__ __launch_bounds__(256) void kF(const float* __restrict__ G2,
                                          const float* __restrict__ Sm,
                                          const float* __restrict__ b0,
                                          const float* __restrict__ W1,
                                          float* __restrict__ z1part) {
    int bid = blockIdx.x;
    int kc = bid & 15;            // 0..15  (64 k each)  -> XCD = kc&7
    int hc = (bid >> 4) & 7;      // 0..7   (128 h-cols each)
    int bs = bid >> 7;            // 0..3   (16 b each)
    int tid = threadIdx.x;

    __shared__ float  W1sh[64][128];   // 32 KB
    __shared__ float4 Ssh4[128][4];    // 8 KB: [r][bg], 4 b-locals per float4
    __shared__ float4 h0t[64][5];      // 5 KB: [k][bg], padded row (5th unused)

    #pragma unroll
    for (int t = 0; t < 32; ++t) {
        int idx = tid + t * 256;      // 0..8191
        int kk = idx >> 7, hcl = idx & 127;
        W1sh[kk][hcl] = W1[(kc * 64 + kk) * 1024 + hc * 128 + hcl];
    }
    {
        float* Sshf = (float*)Ssh4;   // [r][16] b-locals
        #pragma unroll
        for (int t = 0; t < 8; ++t) {
            int idx = tid + t * 256;  // 0..2047
            int bl = idx & 15, r = idx >> 4;
            Sshf[r * 16 + bl] = Sm[(bs * 16 + bl) * 128 + r];
        }
    }
    __syncthreads();

    // ---- Phase A: h0 sub-tile (thread = k-lane x 4-b group) ----
    {
        int k = tid & 63;
        int bg = tid >> 6;            // wave-uniform
        const float* g2p = G2 + kc * 64 + k;
        float4 acc = {0.f, 0.f, 0.f, 0.f};
        #pragma unroll 8
        for (int row = 0; row < 192; ++row) {
            float gv = g2p[row * 1024];
            int r = row & 127;
            float4 sv = Ssh4[r][bg];            // broadcast b128
            acc.x += sv.x * gv; acc.y += sv.y * gv;
            acc.z += sv.z * gv; acc.w += sv.w * gv;
        }
        float base = b0[kc * 64 + k];
        float4 h;
        h.x = fmaxf(base + acc.x, 0.f);
        h.y = fmaxf(base + acc.y, 0.f);
        h.z = fmaxf(base + acc.z, 0.f);
        h.w = fmaxf(base + acc.w, 0.f);
        h0t[k][bg] = h;
    }
    __syncthreads();

    // ---- Phase B: z1part tile = h0 (16x64) . W1sh (64x128) ----
    {
        int hcol = tid & 127;
        int bg2 = tid >> 7;           // 0..1 (8 b each), wave-uniform
        float acc2[8];
        #pragma unroll
        for (int i = 0; i < 8; ++i) acc2[i] = 0.f;
        #pragma unroll 4
        for (int kk = 0; kk < 64; ++kk) {
            float w = W1sh[kk][hcol];
            float4 ha = h0t[kk][bg2 * 2];       // broadcast b128
            float4 hb = h0t[kk][bg2 * 2 + 1];   // broadcast b128
            acc2[0] += ha.x * w; acc2[1] += ha.y * w;
            acc2[2] += ha.z * w; acc2[3] += ha.w * w;
            acc2[4] += hb.x * w; acc2[5] += hb.y * w;
            acc2[6] += hb.z * w; acc2[7] += hb.w * w;
        }
        #pragma unroll
        for (int bb = 0; bb < 8; ++bb) {
            int b = bs * 16 + bg2 * 8 + bb;
            z1part[((size_t)b * 16 + kc) * 1024 + hc * 128 + hcol] = acc2[bb];
        }
    }
}

// kE: out[b] = sum_h relu(b1[h] + sum_kc z1part[b][kc][h]) * Wo[h] + bo
// z1part laid out [b][kc][h] -> each block reads one contiguous 64 KB span.
__global__ __launch_bounds__(1024) void kE(const float* __restrict__ z1part,
                                           const float* __restrict__ b1,
                                           const float* __restrict__ Wo,
                                           const float* __restrict__ bo,
                                           float* __restrict__ out) {
    int b = blockIdx.x;
    int h = threadIdx.x;
    const float* zp = z1part + (size_t)b * 16384 + h;
    float z = b1[h];
    #pragma unroll
    for (int kc = 0; kc < 16; ++kc) z += zp[kc * 1024];
    float acc = fmaxf(z, 0.f) * Wo[h];
    #pragma unroll
    for (int off = 32; off >= 1; off >>= 1) acc += __shfl_down(acc, off);
    __shared__ float red[16];
    if ((h & 63) == 0) red[h >> 6] = acc;
    __syncthreads();
    if (h == 0) {
        float s = bo[0];
        #pragma unroll
        for (int i = 0; i < 16; ++i) s += red[i];
        out[b] = s;
    }
}

extern "C" void kernel_launch(void* const* d_in, const int* in_sizes, int n_in,
                              void* d_out, int out_size, void* d_ws, size_t ws_size,
                              hipStream_t stream) {
    const int*   x     = (const int*)d_in[0];    // (64,128) 0/1
    const int*   masks = (const int*)d_in[1];    // (3,128) 0/1
    const float* W0    = (const float*)d_in[2];  // (8256,1024)
    const float* b0    = (const float*)d_in[3];  // (1024)
    const float* W1    = (const float*)d_in[4];  // (1024,1024)
    const float* b1    = (const float*)d_in[5];  // (1024)
    const float* Wo    = (const float*)d_in[6];  // (1024,1)
    const float* bo    = (const float*)d_in[7];  // (1)
    float* out = (float*)d_out;                  // (64,1)

    char* ws = (char*)d_ws;
    float* Sm     = (float*)(ws);                      // 64*128*4      = 32 KB
    float* G2     = (float*)(ws + (32u  << 10));       // 192*1024*4    = 768 KB
    float* z1part = (float*)(ws + (800u << 10));       // 64*16*1024*4  = 4 MB

    kB<<<769, 256, 0, stream>>>(x, masks, W0, Sm, G2);
    kF<<<512, 256, 0, stream>>>(G2, Sm, b0, W1, z1part);
    kE<<<64, 1024, 0, stream>>>(z1part, b1, Wo, bo, out);
}

// Round 14
// 34.642 us; speedup vs baseline: 1.1303x; 1.0017x over previous
//
#include <hip/hip_runtime.h>
#include <cstdint>

#define DEVFN __device__ __forceinline__

struct U128 { unsigned long long lo, hi; };

// rotate right by s (1..127): bit q of result = bit (q+s)%128 of w
DEVFN U128 rotr128(U128 w, int s) {
    U128 r;
    if (s == 64) { r.lo = w.hi; r.hi = w.lo; return r; }
    if (s < 64) {
        r.lo = (w.lo >> s) | (w.hi << (64 - s));
        r.hi = (w.hi >> s) | (w.lo << (64 - s));
    } else {
        int t = s - 64;
        unsigned long long lo = w.hi, hi = w.lo;
        r.lo = (lo >> t) | (hi << (64 - t));
        r.hi = (hi >> t) | (lo << (64 - t));
    }
    return r;
}

// logical shift right by s (1..127)
DEVFN U128 shr128(U128 w, int s) {
    U128 r;
    if (s == 64) { r.lo = w.hi; r.hi = 0ull; return r; }
    if (s < 64) {
        r.lo = (w.lo >> s) | (w.hi << (64 - s));
        r.hi = w.hi >> s;
    } else {
        r.lo = w.hi >> (s - 64); r.hi = 0ull;
    }
    return r;
}

// KB: W0 -> G2 reduction (768 blocks) + Sm computation (block 768).
// R10-identical except block 768 also initializes out[b] = bo (consumed by
// kE's atomic accumulation two nodes later).
__global__ __launch_bounds__(256) void kB(const int* __restrict__ x,
                                          const int* __restrict__ masks,
                                          const float* __restrict__ W0,
                                          const float* __restrict__ bo,
                                          float* __restrict__ Sm,
                                          float* __restrict__ G2,
                                          float* __restrict__ out) {
    int bid = blockIdx.x;
    int tid = threadIdx.x;

    if (bid == 768) {
        if (tid < 64) out[tid] = bo[0];
        int b = tid >> 2;        // 64 rows of x
        int rc = tid & 3;        // 4 chunks of 32 r's
        const int* xb = x + b * 128;
        U128 w; w.lo = 0ull; w.hi = 0ull;
        #pragma unroll
        for (int p = 0; p < 64; ++p) w.lo |= (unsigned long long)(xb[p] & 1) << p;
        #pragma unroll
        for (int p = 0; p < 64; ++p) w.hi |= (unsigned long long)(xb[64 + p] & 1) << p;
        int r0 = rc * 32;
        if (r0 & 32) { U128 t = rotr128(w, 32); w.lo ^= t.lo; w.hi ^= t.hi; }
        if (r0 & 64) { U128 t = rotr128(w, 64); w.lo ^= t.lo; w.hi ^= t.hi; }
        for (int rr = 0; rr < 32; ++rr) {
            int r = r0 + rr;
            int pc = __popcll(w.lo) + __popcll(w.hi);
            int sv = (r == 0) ? pc : (128 - pc);
            Sm[b * 128 + r] = (float)(2 * sv - 128);
            U128 t = rotr128(w, 1);
            w.lo ^= t.lo; w.hi ^= t.hi;
        }
        return;
    }

    int hc = bid & 3;            // 4 quarters of 256 h
    int y  = bid >> 2;           // 0..191 (r, segment) task
    int r, jstart, jend, slice;
    if (y < 128) { r = y >> 1; slice = y & 1; jstart = slice * 64; jend = (slice == 0) ? 64 : (128 - r); }
    else         { r = y - 64;  slice = 0;    jstart = 0;          jend = 128 - r; }
    int L = jend - jstart;       // 1..64

    int lane = tid & 63;
    int g    = tid >> 6;         // row-group 0..3

    __shared__ unsigned long long mw[3][2];
    __shared__ float cG[64];
    __shared__ float4 partG[4][64];

    if (tid < 128) {
        int half = tid >> 6;
        int lane_ = tid & 63;
        #pragma unroll
        for (int k = 0; k < 3; ++k) {
            unsigned long long bal = __ballot(masks[k * 128 + half * 64 + lane_] & 1);
            if (lane_ == 0) mw[k][half] = bal;
        }
    }
    __syncthreads();
    if (tid < 64) {
        int j = jstart + tid;
        int c = 0;
        #pragma unroll
        for (int k = 0; k < 3; ++k) {
            U128 m; m.lo = mw[k][0]; m.hi = mw[k][1];
            #pragma unroll
            for (int s = 1; s <= 64; s <<= 1) {
                if (r & s) { U128 t = shr128(m, s); m.lo ^= t.lo; m.hi ^= t.hi; }
            }
            int bit = (j < 64) ? (int)((m.lo >> j) & 1) : (int)((m.hi >> (j - 64)) & 1);
            c += bit;
        }
        cG[tid] = (float)(2 - c) * (1.0f / 256.0f);
    }
    __syncthreads();

    int off = r * 128 - (r * (r - 1)) / 2;
    const float* base = W0 + (size_t)(off + jstart) * 1024 + hc * 256 + lane * 4;
    float4 aG = {0.f, 0.f, 0.f, 0.f};
    #pragma unroll 4
    for (int jj = g; jj < L; jj += 4) {
        float4 v = *(const float4*)(base + (size_t)jj * 1024);
        float cg = cG[jj];
        aG.x += cg * v.x; aG.y += cg * v.y; aG.z += cg * v.z; aG.w += cg * v.w;
    }
    partG[g][lane] = aG;
    __syncthreads();

    if (tid < 64) {
        float4 sG = partG[0][tid];
        #pragma unroll
        for (int gg = 1; gg < 4; ++gg) {
            float4 pG = partG[gg][tid];
            sG.x += pG.x; sG.y += pG.y; sG.z += pG.z; sG.w += pG.w;
        }
        int row = slice * 128 + r;
        *(float4*)(G2 + (size_t)row * 1024 + hc * 256 + tid * 4) = sG;
    }
}

// kF: fused layer-1 + layer-2 split-K. Byte-identical to the R10 winner.
__global__ __launch_bounds__(256) void kF(const float* __restrict__ G2,
                                          const float* __restrict__ Sm,
                                          const float* __restrict__ b0,
                                          const float* __restrict__ W1,
                                          float* __restrict__ z1part) {
    int bid = blockIdx.x;
    int kc = bid & 15;            // 0..15  (64 k each)  -> XCD = kc&7
    int hc = (bid >> 4) & 7;      // 0..7   (128 h-cols each)
    int bs = bid >> 7;            // 0..3   (16 b each)
    int tid = threadIdx.x;

    __shared__ float W1sh[64][128];   // 32 KB
    __shared__ float Ssh[16][128];    // 8 KB (pre-shifted S - 128)
    __shared__ float h0sh[16][64];    // 4 KB

    #pragma unroll
    for (int t = 0; t < 32; ++t) {
        int idx = tid + t * 256;      // 0..8191
        int kk = idx >> 7, hcl = idx & 127;
        W1sh[kk][hcl] = W1[(kc * 64 + kk) * 1024 + hc * 128 + hcl];
    }
    #pragma unroll
    for (int t = 0; t < 8; ++t) {
        int idx = tid + t * 256;      // 0..2047
        int bl = idx >> 7, r = idx & 127;
        Ssh[bl][r] = Sm[(bs * 16 + bl) * 128 + r];
    }
    __syncthreads();

    // ---- Phase A: h0 sub-tile ----
    {
        int k = tid & 63;
        int bg = tid >> 6;
        const float* g2p = G2 + kc * 64 + k;
        float acc[4] = {0.f, 0.f, 0.f, 0.f};
        #pragma unroll 8
        for (int row = 0; row < 192; ++row) {
            float gv = g2p[row * 1024];
            int r = row & 127;
            #pragma unroll
            for (int bb = 0; bb < 4; ++bb)
                acc[bb] += Ssh[bg * 4 + bb][r] * gv;
        }
        float base = b0[kc * 64 + k];
        #pragma unroll
        for (int bb = 0; bb < 4; ++bb)
            h0sh[bg * 4 + bb][k] = fmaxf(base + acc[bb], 0.f);
    }
    __syncthreads();

    // ---- Phase B: z1part tile = h0sh (16x64) . W1sh (64x128) ----
    {
        int hcol = tid & 127;
        int bg2 = tid >> 7;
        float acc2[8];
        #pragma unroll
        for (int i = 0; i < 8; ++i) acc2[i] = 0.f;
        #pragma unroll 4
        for (int kk = 0; kk < 64; ++kk) {
            float w = W1sh[kk][hcol];
            #pragma unroll
            for (int bb = 0; bb < 8; ++bb)
                acc2[bb] += h0sh[bg2 * 8 + bb][kk] * w;
        }
        #pragma unroll
        for (int bb = 0; bb < 8; ++bb) {
            int b = bs * 16 + bg2 * 8 + bb;
            z1part[((size_t)b * 16 + kc) * 1024 + hc * 128 + hcol] = acc2[bb];
        }
    }
}

// kE: 256 blocks (64 b x 4 h-quarters); each block reduces 256 h and does one
// fp32 atomic add into out[b] (pre-initialized to bo by kB).
__global__ __launch_bounds__(256) void kE(const float* __restrict__ z1part,
                                          const float* __restrict__ b1,
                                          const float* __restrict__ Wo,
                                          float* __restrict__ out) {
    int b = blockIdx.x & 63;
    int q = blockIdx.x >> 6;      // h-quarter 0..3
    int tid = threadIdx.x;
    int h = q * 256 + tid;
    const float* zp = z1part + (size_t)b * 16384 + h;
    float z = b1[h];
    #pragma unroll
    for (int kc = 0; kc < 16; ++kc) z += zp[kc * 1024];
    float acc = fmaxf(z, 0.f) * Wo[h];
    #pragma unroll
    for (int off = 32; off >= 1; off >>= 1) acc += __shfl_down(acc, off);
    __shared__ float red[4];
    if ((tid & 63) == 0) red[tid >> 6] = acc;
    __syncthreads();
    if (tid == 0) unsafeAtomicAdd(&out[b], red[0] + red[1] + red[2] + red[3]);
}

extern "C" void kernel_launch(void* const* d_in, const int* in_sizes, int n_in,
                              void* d_out, int out_size, void* d_ws, size_t ws_size,
                              hipStream_t stream) {
    const int*   x     = (const int*)d_in[0];    // (64,128) 0/1
    const int*   masks = (const int*)d_in[1];    // (3,128) 0/1
    const float* W0    = (const float*)d_in[2];  // (8256,1024)
    const float* b0    = (const float*)d_in[3];  // (1024)
    const float* W1    = (const float*)d_in[4];  // (1024,1024)
    const float* b1    = (const float*)d_in[5];  // (1024)
    const float* Wo    = (const float*)d_in[6];  // (1024,1)
    const float* bo    = (const float*)d_in[7];  // (1)
    float* out = (float*)d_out;                  // (64,1)

    char* ws = (char*)d_ws;
    float* Sm     = (float*)(ws);                      // 64*128*4      = 32 KB
    float* G2     = (float*)(ws + (32u  << 10));       // 192*1024*4    = 768 KB
    float* z1part = (float*)(ws + (800u << 10));       // 64*16*1024*4  = 4 MB

    kB<<<769, 256, 0, stream>>>(x, masks, W0, bo, Sm, G2, out);
    kF<<<512, 256, 0, stream>>>(G2, Sm, b0, W1, z1part);
    kE<<<256, 256, 0, stream>>>(z1part, b1, Wo, out);
}

// Round 15
// 33.873 us; speedup vs baseline: 1.1560x; 1.0227x over previous
//
#include <hip/hip_runtime.h>
#include <cstdint>

#define DEVFN __device__ __forceinline__

struct U128 { unsigned long long lo, hi; };

// rotate right by s (1..127): bit q of result = bit (q+s)%128 of w
DEVFN U128 rotr128(U128 w, int s) {
    U128 r;
    if (s == 64) { r.lo = w.hi; r.hi = w.lo; return r; }
    if (s < 64) {
        r.lo = (w.lo >> s) | (w.hi << (64 - s));
        r.hi = (w.hi >> s) | (w.lo << (64 - s));
    } else {
        int t = s - 64;
        unsigned long long lo = w.hi, hi = w.lo;
        r.lo = (lo >> t) | (hi << (64 - t));
        r.hi = (hi >> t) | (lo << (64 - t));
    }
    return r;
}

// logical shift right by s (1..127)
DEVFN U128 shr128(U128 w, int s) {
    U128 r;
    if (s == 64) { r.lo = w.hi; r.hi = 0ull; return r; }
    if (s < 64) {
        r.lo = (w.lo >> s) | (w.hi << (64 - s));
        r.hi = w.hi >> s;
    } else {
        r.lo = w.hi >> (s - 64); r.hi = 0ull;
    }
    return r;
}

// KB: W0 -> G2 reduction (768 blocks) + Sm computation (block 768).
// Uses the identity cA = -128*cG: only the G-weighted sums are needed;
// Sm[b][r] = S[b][r] - 128 is stored pre-shifted.
__global__ __launch_bounds__(256) void kB(const int* __restrict__ x,
                                          const int* __restrict__ masks,
                                          const float* __restrict__ W0,
                                          float* __restrict__ Sm,
                                          float* __restrict__ G2) {
    int bid = blockIdx.x;
    int tid = threadIdx.x;

    if (bid == 768) {
        int b = tid >> 2;        // 64 rows of x
        int rc = tid & 3;        // 4 chunks of 32 r's
        const int* xb = x + b * 128;
        U128 w; w.lo = 0ull; w.hi = 0ull;
        #pragma unroll
        for (int p = 0; p < 64; ++p) w.lo |= (unsigned long long)(xb[p] & 1) << p;
        #pragma unroll
        for (int p = 0; p < 64; ++p) w.hi |= (unsigned long long)(xb[64 + p] & 1) << p;
        int r0 = rc * 32;
        if (r0 & 32) { U128 t = rotr128(w, 32); w.lo ^= t.lo; w.hi ^= t.hi; }
        if (r0 & 64) { U128 t = rotr128(w, 64); w.lo ^= t.lo; w.hi ^= t.hi; }
        for (int rr = 0; rr < 32; ++rr) {
            int r = r0 + rr;
            int pc = __popcll(w.lo) + __popcll(w.hi);
            int sv = (r == 0) ? pc : (128 - pc);
            Sm[b * 128 + r] = (float)(2 * sv - 128);
            U128 t = rotr128(w, 1);
            w.lo ^= t.lo; w.hi ^= t.hi;
        }
        return;
    }

    int hc = bid & 3;            // 4 quarters of 256 h
    int y  = bid >> 2;           // 0..191 (r, segment) task
    int r, jstart, jend, slice;
    if (y < 128) { r = y >> 1; slice = y & 1; jstart = slice * 64; jend = (slice == 0) ? 64 : (128 - r); }
    else         { r = y - 64;  slice = 0;    jstart = 0;          jend = 128 - r; }
    int L = jend - jstart;       // 1..64

    int lane = tid & 63;
    int g    = tid >> 6;         // row-group 0..3

    __shared__ unsigned long long mw[3][2];
    __shared__ float cG[64];
    __shared__ float4 partG[4][64];

    if (tid < 128) {
        int half = tid >> 6;
        int lane_ = tid & 63;
        #pragma unroll
        for (int k = 0; k < 3; ++k) {
            unsigned long long bal = __ballot(masks[k * 128 + half * 64 + lane_] & 1);
            if (lane_ == 0) mw[k][half] = bal;
        }
    }
    __syncthreads();
    if (tid < 64) {
        int j = jstart + tid;
        int c = 0;
        #pragma unroll
        for (int k = 0; k < 3; ++k) {
            U128 m; m.lo = mw[k][0]; m.hi = mw[k][1];
            #pragma unroll
            for (int s = 1; s <= 64; s <<= 1) {
                if (r & s) { U128 t = shr128(m, s); m.lo ^= t.lo; m.hi ^= t.hi; }
            }
            int bit = (j < 64) ? (int)((m.lo >> j) & 1) : (int)((m.hi >> (j - 64)) & 1);
            c += bit;
        }
        cG[tid] = (float)(2 - c) * (1.0f / 256.0f);
    }
    __syncthreads();

    int off = r * 128 - (r * (r - 1)) / 2;
    const float* base = W0 + (size_t)(off + jstart) * 1024 + hc * 256 + lane * 4;
    float4 aG = {0.f, 0.f, 0.f, 0.f};
    #pragma unroll 4
    for (int jj = g; jj < L; jj += 4) {
        float4 v = *(const float4*)(base + (size_t)jj * 1024);
        float cg = cG[jj];
        aG.x += cg * v.x; aG.y += cg * v.y; aG.z += cg * v.z; aG.w += cg * v.w;
    }
    partG[g][lane] = aG;
    __syncthreads();

    if (tid < 64) {
        float4 sG = partG[0][tid];
        #pragma unroll
        for (int gg = 1; gg < 4; ++gg) {
            float4 pG = partG[gg][tid];
            sG.x += pG.x; sG.y += pG.y; sG.z += pG.z; sG.w += pG.w;
        }
        int row = slice * 128 + r;
        *(float4*)(G2 + (size_t)row * 1024 + hc * 256 + tid * 4) = sG;
    }
}

// kF: fused layer-1 + layer-2 split-K. 1-D grid of 512; kc = bid&15 so all 32
// blocks sharing a kc (same G2 columns + W1 rows) land on one XCD (bid%8).
// Phase A: h0[b][k] = relu(b0[k] + sum_row Sm[b][row&127] * G2[row][k])
// Phase B: z1part[b][kc][hc-slice] = h0 . W1tile
__global__ __launch_bounds__(256) void kF(const float* __restrict__ G2,
                                          const float* __restrict__ Sm,
                                          const float* __restrict__ b0,
                                          const float* __restrict__ W1,
                                          float* __restrict__ z1part) {
    int bid = blockIdx.x;
    int kc = bid & 15;            // 0..15  (64 k each)  -> XCD = kc&7
    int hc = (bid >> 4) & 7;      // 0..7   (128 h-cols each)
    int bs = bid >> 7;            // 0..3   (16 b each)
    int tid = threadIdx.x;

    __shared__ float W1sh[64][128];   // 32 KB
    __shared__ float Ssh[16][128];    // 8 KB (pre-shifted S - 128)
    __shared__ float h0sh[16][64];    // 4 KB

    #pragma unroll
    for (int t = 0; t < 32; ++t) {
        int idx = tid + t * 256;      // 0..8191
        int kk = idx >> 7, hcl = idx & 127;
        W1sh[kk][hcl] = W1[(kc * 64 + kk) * 1024 + hc * 128 + hcl];
    }
    #pragma unroll
    for (int t = 0; t < 8; ++t) {
        int idx = tid + t * 256;      // 0..2047
        int bl = idx >> 7, r = idx & 127;
        Ssh[bl][r] = Sm[(bs * 16 + bl) * 128 + r];
    }
    __syncthreads();

    // ---- Phase A: h0 sub-tile ----
    {
        int k = tid & 63;
        int bg = tid >> 6;
        const float* g2p = G2 + kc * 64 + k;
        float acc[4] = {0.f, 0.f, 0.f, 0.f};
        #pragma unroll 8
        for (int row = 0; row < 192; ++row) {
            float gv = g2p[row * 1024];
            int r = row & 127;
            #pragma unroll
            for (int bb = 0; bb < 4; ++bb)
                acc[bb] += Ssh[bg * 4 + bb][r] * gv;
        }
        float base = b0[kc * 64 + k];
        #pragma unroll
        for (int bb = 0; bb < 4; ++bb)
            h0sh[bg * 4 + bb][k] = fmaxf(base + acc[bb], 0.f);
    }
    __syncthreads();

    // ---- Phase B: z1part tile = h0sh (16x64) . W1sh (64x128) ----
    {
        int hcol = tid & 127;
        int bg2 = tid >> 7;
        float acc2[8];
        #pragma unroll
        for (int i = 0; i < 8; ++i) acc2[i] = 0.f;
        #pragma unroll 4
        for (int kk = 0; kk < 64; ++kk) {
            float w = W1sh[kk][hcol];
            #pragma unroll
            for (int bb = 0; bb < 8; ++bb)
                acc2[bb] += h0sh[bg2 * 8 + bb][kk] * w;
        }
        #pragma unroll
        for (int bb = 0; bb < 8; ++bb) {
            int b = bs * 16 + bg2 * 8 + bb;
            z1part[((size_t)b * 16 + kc) * 1024 + hc * 128 + hcol] = acc2[bb];
        }
    }
}

// kE: out[b] = sum_h relu(b1[h] + sum_kc z1part[b][kc][h]) * Wo[h] + bo
// z1part laid out [b][kc][h] -> each block reads one contiguous 64 KB span.
__global__ __launch_bounds__(1024) void kE(const float* __restrict__ z1part,
                                           const float* __restrict__ b1,
                                           const float* __restrict__ Wo,
                                           const float* __restrict__ bo,
                                           float* __restrict__ out) {
    int b = blockIdx.x;
    int h = threadIdx.x;
    const float* zp = z1part + (size_t)b * 16384 + h;
    float z = b1[h];
    #pragma unroll
    for (int kc = 0; kc < 16; ++kc) z += zp[kc * 1024];
    float acc = fmaxf(z, 0.f) * Wo[h];
    #pragma unroll
    for (int off = 32; off >= 1; off >>= 1) acc += __shfl_down(acc, off);
    __shared__ float red[16];
    if ((h & 63) == 0) red[h >> 6] = acc;
    __syncthreads();
    if (h == 0) {
        float s = bo[0];
        #pragma unroll
        for (int i = 0; i < 16; ++i) s += red[i];
        out[b] = s;
    }
}

extern "C" void kernel_launch(void* const* d_in, const int* in_sizes, int n_in,
                              void* d_out, int out_size, void* d_ws, size_t ws_size,
                              hipStream_t stream) {
    const int*   x     = (const int*)d_in[0];    // (64,128) 0/1
    const int*   masks = (const int*)d_in[1];    // (3,128) 0/1
    const float* W0    = (const float*)d_in[2];  // (8256,1024)
    const float* b0    = (const float*)d_in[3];  // (1024)
    const float* W1    = (const float*)d_in[4];  // (1024,1024)
    const float* b1    = (const float*)d_in[5];  // (1024)
    const float* Wo    = (const float*)d_in[6];  // (1024,1)
    const float* bo    = (const float*)d_in[7];  // (1)
    float* out = (float*)d_out;                  // (64,1)

    char* ws = (char*)d_ws;
    float* Sm     = (float*)(ws);                      // 64*128*4      = 32 KB
    float* G2     = (float*)(ws + (32u  << 10));       // 192*1024*4    = 768 KB
    float* z1part = (float*)(ws + (800u << 10));       // 64*16*1024*4  = 4 MB

    kB<<<769, 256, 0, stream>>>(x, masks, W0, Sm, G2);
    kF<<<512, 256, 0, stream>>>(G2, Sm, b0, W1, z1part);
    kE<<<64, 1024, 0, stream>>>(z1part, b1, Wo, bo, out);
}